// Round 1
// baseline (7568.093 us; speedup 1.0000x reference)
//
#include <hip/hip_runtime.h>
#include <math.h>

// Problem constants
#define N_TOK 2048
#define H_DIM 4096
#define NH 32
#define NKV 8
#define HD 128
#define QKV_D 6144   // (NH + 2*NKV) * HD
#define NE 8
#define TOPK 2

// d_out layout (floats): permuted_output | topk_weights | topk_ids | reorder_ids
#define OUT_PERM 0
#define OUT_W    16777216   // 4096*4096
#define OUT_IDS  16781312
#define OUT_REO  16785408

// ---------------- RMSNorm ----------------
__global__ __launch_bounds__(256) void rmsnorm_k(const float* __restrict__ x,
                                                 const float* __restrict__ w,
                                                 float* __restrict__ y) {
    int row = blockIdx.x;
    int tid = threadIdx.x;
    const float4* x4 = (const float4*)(x + (size_t)row * H_DIM);
    const float4* w4 = (const float4*)w;
    float4 v[4];
    float ss = 0.f;
#pragma unroll
    for (int k = 0; k < 4; ++k) {
        v[k] = x4[tid + k * 256];
        ss += v[k].x * v[k].x + v[k].y * v[k].y + v[k].z * v[k].z + v[k].w * v[k].w;
    }
#pragma unroll
    for (int off = 32; off; off >>= 1) ss += __shfl_xor(ss, off);
    __shared__ float sacc[4];
    if ((tid & 63) == 0) sacc[tid >> 6] = ss;
    __syncthreads();
    float tot = sacc[0] + sacc[1] + sacc[2] + sacc[3];
    float sc = rsqrtf(tot * (1.0f / H_DIM) + 1e-6f);
    float4* y4 = (float4*)(y + (size_t)row * H_DIM);
#pragma unroll
    for (int k = 0; k < 4; ++k) {
        float4 ww = w4[tid + k * 256];
        float4 o;
        o.x = v[k].x * sc * ww.x;
        o.y = v[k].y * sc * ww.y;
        o.z = v[k].z * sc * ww.z;
        o.w = v[k].w * sc * ww.w;
        y4[tid + k * 256] = o;
    }
}

// ---------------- fp32 tiled GEMM: C[M=2048 x Nc] = A[2048x4096] @ B[4096xNc] (+ residual)
__global__ __launch_bounds__(256) void gemm64_k(const float* __restrict__ A,
                                                const float* __restrict__ B,
                                                float* __restrict__ C, int Nc,
                                                const float* __restrict__ residual) {
    __shared__ float As[16][68];   // [k][m], padded for store conflicts, 16B-aligned rows (68*4=272)
    __shared__ float Bs[16][64];   // [k][n]
    const int K = 4096;
    int tid = threadIdx.x;
    int tx = tid & 15, ty = tid >> 4;
    int m0 = blockIdx.y * 64, n0 = blockIdx.x * 64;
    int la_m = tid >> 2, la_k = (tid & 3) * 4;
    int lb_k = tid >> 4, lb_n = (tid & 15) * 4;
    float acc[4][4] = {};
    for (int k0 = 0; k0 < K; k0 += 16) {
        float4 av = *(const float4*)(A + (size_t)(m0 + la_m) * K + k0 + la_k);
        float4 bv = *(const float4*)(B + (size_t)(k0 + lb_k) * Nc + n0 + lb_n);
        As[la_k + 0][la_m] = av.x;
        As[la_k + 1][la_m] = av.y;
        As[la_k + 2][la_m] = av.z;
        As[la_k + 3][la_m] = av.w;
        *(float4*)&Bs[lb_k][lb_n] = bv;
        __syncthreads();
#pragma unroll
        for (int kk = 0; kk < 16; ++kk) {
            float4 a = *(const float4*)&As[kk][ty * 4];
            float4 b = *(const float4*)&Bs[kk][tx * 4];
            acc[0][0] += a.x * b.x; acc[0][1] += a.x * b.y; acc[0][2] += a.x * b.z; acc[0][3] += a.x * b.w;
            acc[1][0] += a.y * b.x; acc[1][1] += a.y * b.y; acc[1][2] += a.y * b.z; acc[1][3] += a.y * b.w;
            acc[2][0] += a.z * b.x; acc[2][1] += a.z * b.y; acc[2][2] += a.z * b.z; acc[2][3] += a.z * b.w;
            acc[3][0] += a.w * b.x; acc[3][1] += a.w * b.y; acc[3][2] += a.w * b.z; acc[3][3] += a.w * b.w;
        }
        __syncthreads();
    }
#pragma unroll
    for (int i = 0; i < 4; ++i) {
        size_t off = (size_t)(m0 + ty * 4 + i) * Nc + n0 + tx * 4;
        float4 r = make_float4(acc[i][0], acc[i][1], acc[i][2], acc[i][3]);
        if (residual) {
            float4 h = *(const float4*)(residual + off);
            r.x += h.x; r.y += h.y; r.z += h.z; r.w += h.w;
        }
        *(float4*)(C + off) = r;
    }
}

// ---------------- RoPE (NeoX) in-place on q and k heads of qkv ----------------
__global__ __launch_bounds__(64) void rope_k(float* __restrict__ qkv,
                                             const int* __restrict__ pos) {
    int row = blockIdx.x;
    int hh = blockIdx.y;  // 0..39: 0-31 q heads, 32-39 k heads
    int t = threadIdx.x;  // 0..63
    float* p;
    if (hh < NH)
        p = qkv + (size_t)row * QKV_D + hh * HD;
    else
        p = qkv + (size_t)row * QKV_D + NH * HD + (hh - NH) * HD;
    float inv_freq = powf(10000.0f, -(float)(2 * t) * (1.0f / HD));
    float ang = (float)pos[row] * inv_freq;
    float c = cosf(ang), s = sinf(ang);
    float x1 = p[t], x2 = p[t + 64];
    p[t] = x1 * c - x2 * s;
    p[t + 64] = x2 * c + x1 * s;
}

// ---------------- causal GQA flash attention (one wave per q-row) ----------------
__global__ __launch_bounds__(256) void attn_k(const float* __restrict__ qkv,
                                              float* __restrict__ out) {
    int lane = threadIdx.x & 63;
    int wave = threadIdx.x >> 6;
    int i = blockIdx.x * 4 + wave;
    int h = blockIdx.y;
    int kvh = h >> 2;  // group = NH/NKV = 4
    const float* qrow = qkv + (size_t)i * QKV_D + h * HD;
    float2 q = *(const float2*)(qrow + lane * 2);
    const float scale = 0.08838834764831845f;  // 1/sqrt(128)
    q.x *= scale; q.y *= scale;
    float m = -INFINITY, l = 0.f, ax = 0.f, ay = 0.f;
    const float* kbase = qkv + NH * HD + kvh * HD + lane * 2;
    for (int j = 0; j <= i; ++j) {
        const float* kp = kbase + (size_t)j * QKV_D;
        float2 k2 = *(const float2*)kp;
        float2 v2 = *(const float2*)(kp + NKV * HD);  // v block is 1024 floats after k block
        float s = q.x * k2.x + q.y * k2.y;
#pragma unroll
        for (int off = 32; off; off >>= 1) s += __shfl_xor(s, off);
        float mn = fmaxf(m, s);
        float alpha = __expf(m - mn);
        float p = __expf(s - mn);
        l = l * alpha + p;
        ax = ax * alpha + p * v2.x;
        ay = ay * alpha + p * v2.y;
        m = mn;
    }
    float inv = 1.f / l;
    *(float2*)(out + (size_t)i * (NH * HD) + h * HD + lane * 2) = make_float2(ax * inv, ay * inv);
}

// ---------------- top-2 routing ----------------
__global__ __launch_bounds__(256) void topk_k(const float* __restrict__ elog,
                                              float* __restrict__ w_out,
                                              float* __restrict__ id_out,
                                              int* __restrict__ ids_int) {
    int row = blockIdx.x * 256 + threadIdx.x;
    if (row >= N_TOK) return;
    const float4* e4 = (const float4*)(elog + (size_t)row * NE);
    float4 a = e4[0], b = e4[1];
    float e[8] = {a.x, a.y, a.z, a.w, b.x, b.y, b.z, b.w};
    int id0 = 0;
    float b0 = e[0];
#pragma unroll
    for (int t = 1; t < 8; ++t)
        if (e[t] > b0) { b0 = e[t]; id0 = t; }
    int id1 = -1;
    float b1 = -INFINITY;
#pragma unroll
    for (int t = 0; t < 8; ++t)
        if (t != id0 && e[t] > b1) { b1 = e[t]; id1 = t; }
    float s = b0 + b1;
    w_out[row * 2 + 0] = b0 / s;
    w_out[row * 2 + 1] = b1 / s;
    id_out[row * 2 + 0] = (float)id0;
    id_out[row * 2 + 1] = (float)id1;
    ids_int[row * 2 + 0] = id0;
    ids_int[row * 2 + 1] = id1;
}

// ---------------- stable argsort of 4096 expert ids (counting rank) ----------------
__global__ __launch_bounds__(256) void sort_k(const int* __restrict__ ids,
                                              float* __restrict__ reorder_out,
                                              int* __restrict__ perm) {
    __shared__ int sh[N_TOK * TOPK];
    int tid = threadIdx.x;
    for (int r = tid; r < N_TOK * TOPK; r += 256) sh[r] = ids[r];
    __syncthreads();
    int i = blockIdx.x * 256 + tid;
    int e = sh[i];
    int rank = 0;
    for (int j = 0; j < N_TOK * TOPK; ++j) {
        int ej = sh[j];
        rank += (ej < e) ? 1 : ((ej == e && j < i) ? 1 : 0);
    }
    reorder_out[rank] = (float)i;
    perm[rank] = i;
}

// ---------------- permuted row gather ----------------
__global__ __launch_bounds__(256) void gather_k(const float* __restrict__ src,
                                                const int* __restrict__ perm,
                                                float* __restrict__ dst) {
    int r = blockIdx.x;
    int srow = perm[r] >> 1;  // // TOPK
    const float4* s4 = (const float4*)(src + (size_t)srow * H_DIM);
    float4* d4 = (float4*)(dst + (size_t)r * H_DIM);
    int tid = threadIdx.x;
#pragma unroll
    for (int k = 0; k < 4; ++k) d4[tid + k * 256] = s4[tid + k * 256];
}

extern "C" void kernel_launch(void* const* d_in, const int* in_sizes, int n_in,
                              void* d_out, int out_size, void* d_ws, size_t ws_size,
                              hipStream_t stream) {
    const int*   positions = (const int*)d_in[0];
    const float* hidden    = (const float*)d_in[1];
    const float* w_qkv     = (const float*)d_in[2];
    const float* w_o       = (const float*)d_in[3];
    // d_in[4] = w_gate: dead code in reference (router_logits unused)
    const float* rms_pre   = (const float*)d_in[5];
    const float* rms_post  = (const float*)d_in[6];
    const float* elog      = (const float*)d_in[7];
    float* out = (float*)d_out;

    char* ws = (char*)d_ws;
    float* bufA = (float*)(ws);                    // 32 MB: x_norm, later s
    float* bufB = (float*)(ws + 33554432ULL);      // 48+ MB: qkv
    float* bufC = (float*)(ws + 83886080ULL);      // 32 MB: attn_out
    float* bufD = (float*)(ws + 117440512ULL);     // 32 MB: out2 (post-norm)
    int* ids_int = (int*)(ws + 150994944ULL);      // 16 KB
    int* perm_int = (int*)(ws + 151011328ULL);     // 16 KB

    // 1. pre-attention RMSNorm
    rmsnorm_k<<<N_TOK, 256, 0, stream>>>(hidden, rms_pre, bufA);
    // 2. QKV projection: (2048x4096) @ (4096x6144)
    gemm64_k<<<dim3(QKV_D / 64, N_TOK / 64), 256, 0, stream>>>(bufA, w_qkv, bufB, QKV_D, nullptr);
    // 3. RoPE on q (32 heads) + k (8 heads), in place
    rope_k<<<dim3(N_TOK, NH + NKV), 64, 0, stream>>>(bufB, positions);
    // 4. causal GQA attention
    attn_k<<<dim3(N_TOK / 4, NH), 256, 0, stream>>>(bufB, bufC);
    // 5. output projection + residual: (2048x4096) @ (4096x4096) + hidden
    gemm64_k<<<dim3(H_DIM / 64, N_TOK / 64), 256, 0, stream>>>(bufC, w_o, bufA, H_DIM, hidden);
    // 6. post-attention RMSNorm
    rmsnorm_k<<<N_TOK, 256, 0, stream>>>(bufA, rms_post, bufD);
    // 7. top-2 expert selection
    topk_k<<<N_TOK / 256, 256, 0, stream>>>(elog, out + OUT_W, out + OUT_IDS, ids_int);
    // 8. stable argsort of flattened expert ids
    sort_k<<<(N_TOK * TOPK) / 256, 256, 0, stream>>>(ids_int, out + OUT_REO, perm_int);
    // 9. permuted gather of post-norm output rows
    gather_k<<<N_TOK * TOPK, 256, 0, stream>>>(bufD, perm_int, out + OUT_PERM);
}

// Round 2
// 4211.452 us; speedup vs baseline: 1.7970x; 1.7970x over previous
//
#include <hip/hip_runtime.h>
#include <math.h>

// Problem constants
#define N_TOK 2048
#define H_DIM 4096
#define NH 32
#define NKV 8
#define HD 128
#define QKV_D 6144   // (NH + 2*NKV) * HD
#define NE 8
#define TOPK 2

// d_out layout (floats): permuted_output | topk_weights | topk_ids | reorder_ids
#define OUT_PERM 0
#define OUT_W    16777216   // 4096*4096
#define OUT_IDS  16781312
#define OUT_REO  16785408

// ---------------- RMSNorm ----------------
__global__ __launch_bounds__(256) void rmsnorm_k(const float* __restrict__ x,
                                                 const float* __restrict__ w,
                                                 float* __restrict__ y) {
    int row = blockIdx.x;
    int tid = threadIdx.x;
    const float4* x4 = (const float4*)(x + (size_t)row * H_DIM);
    const float4* w4 = (const float4*)w;
    float4 v[4];
    float ss = 0.f;
#pragma unroll
    for (int k = 0; k < 4; ++k) {
        v[k] = x4[tid + k * 256];
        ss += v[k].x * v[k].x + v[k].y * v[k].y + v[k].z * v[k].z + v[k].w * v[k].w;
    }
#pragma unroll
    for (int off = 32; off; off >>= 1) ss += __shfl_xor(ss, off);
    __shared__ float sacc[4];
    if ((tid & 63) == 0) sacc[tid >> 6] = ss;
    __syncthreads();
    float tot = sacc[0] + sacc[1] + sacc[2] + sacc[3];
    float sc = rsqrtf(tot * (1.0f / H_DIM) + 1e-6f);
    float4* y4 = (float4*)(y + (size_t)row * H_DIM);
#pragma unroll
    for (int k = 0; k < 4; ++k) {
        float4 ww = w4[tid + k * 256];
        float4 o;
        o.x = v[k].x * sc * ww.x;
        o.y = v[k].y * sc * ww.y;
        o.z = v[k].z * sc * ww.z;
        o.w = v[k].w * sc * ww.w;
        y4[tid + k * 256] = o;
    }
}

// ---------------- fp32 tiled GEMM: C[M=2048 x Nc] = A[2048x4096] @ B[4096xNc] (+ residual)
__global__ __launch_bounds__(256) void gemm64_k(const float* __restrict__ A,
                                                const float* __restrict__ B,
                                                float* __restrict__ C, int Nc,
                                                const float* __restrict__ residual) {
    __shared__ float As[16][68];
    __shared__ float Bs[16][64];
    const int K = 4096;
    int tid = threadIdx.x;
    int tx = tid & 15, ty = tid >> 4;
    int m0 = blockIdx.y * 64, n0 = blockIdx.x * 64;
    int la_m = tid >> 2, la_k = (tid & 3) * 4;
    int lb_k = tid >> 4, lb_n = (tid & 15) * 4;
    float acc[4][4] = {};
    for (int k0 = 0; k0 < K; k0 += 16) {
        float4 av = *(const float4*)(A + (size_t)(m0 + la_m) * K + k0 + la_k);
        float4 bv = *(const float4*)(B + (size_t)(k0 + lb_k) * Nc + n0 + lb_n);
        As[la_k + 0][la_m] = av.x;
        As[la_k + 1][la_m] = av.y;
        As[la_k + 2][la_m] = av.z;
        As[la_k + 3][la_m] = av.w;
        *(float4*)&Bs[lb_k][lb_n] = bv;
        __syncthreads();
#pragma unroll
        for (int kk = 0; kk < 16; ++kk) {
            float4 a = *(const float4*)&As[kk][ty * 4];
            float4 b = *(const float4*)&Bs[kk][tx * 4];
            acc[0][0] += a.x * b.x; acc[0][1] += a.x * b.y; acc[0][2] += a.x * b.z; acc[0][3] += a.x * b.w;
            acc[1][0] += a.y * b.x; acc[1][1] += a.y * b.y; acc[1][2] += a.y * b.z; acc[1][3] += a.y * b.w;
            acc[2][0] += a.z * b.x; acc[2][1] += a.z * b.y; acc[2][2] += a.z * b.z; acc[2][3] += a.z * b.w;
            acc[3][0] += a.w * b.x; acc[3][1] += a.w * b.y; acc[3][2] += a.w * b.z; acc[3][3] += a.w * b.w;
        }
        __syncthreads();
    }
#pragma unroll
    for (int i = 0; i < 4; ++i) {
        size_t off = (size_t)(m0 + ty * 4 + i) * Nc + n0 + tx * 4;
        float4 r = make_float4(acc[i][0], acc[i][1], acc[i][2], acc[i][3]);
        if (residual) {
            float4 h = *(const float4*)(residual + off);
            r.x += h.x; r.y += h.y; r.z += h.z; r.w += h.w;
        }
        *(float4*)(C + off) = r;
    }
}

// ---------------- RoPE (NeoX) in-place on q and k heads of qkv ----------------
__global__ __launch_bounds__(64) void rope_k(float* __restrict__ qkv,
                                             const int* __restrict__ pos) {
    int row = blockIdx.x;
    int hh = blockIdx.y;  // 0..39: 0-31 q heads, 32-39 k heads
    int t = threadIdx.x;  // 0..63
    float* p;
    if (hh < NH)
        p = qkv + (size_t)row * QKV_D + hh * HD;
    else
        p = qkv + (size_t)row * QKV_D + NH * HD + (hh - NH) * HD;
    float inv_freq = powf(10000.0f, -(float)(2 * t) * (1.0f / HD));
    float ang = (float)pos[row] * inv_freq;
    float c = cosf(ang), s = sinf(ang);
    float x1 = p[t], x2 = p[t + 64];
    p[t] = x1 * c - x2 * s;
    p[t + 64] = x2 * c + x1 * s;
}

// ---------------- tiled fp32 flash attention ----------------
// block = (64 q-rows, 1 head), 256 threads (4 waves)
// score thread layout: rg = tid>>4 -> rows rg*4..+3 ; c = tid&15 -> key col
// PV thread layout:    same rows   ; dc = tid&15 -> d-chunks [dc*4, dc*4+3] and [64+dc*4, ...]
#define QT 64
#define JT 16
__global__ __launch_bounds__(256) void attn_k(const float* __restrict__ qkv,
                                              float* __restrict__ out) {
    __shared__ float qs[QT][132];   // padded: +16B per row
    __shared__ float ks[JT][132];
    __shared__ float vs[JT][132];
    __shared__ float pt[JT][68];    // P transposed: [j][row], padded

    int tid = threadIdx.x;
    int h = blockIdx.y;
    int kvh = h >> 2;                        // NH/NKV = 4
    int qtile = gridDim.x - 1 - blockIdx.x;  // heavy tiles dispatched first
    int i0 = qtile * QT;

    const float scale = 0.08838834764831845f;  // 1/sqrt(128)

    // stage Q tile (scaled)
#pragma unroll
    for (int it = 0; it < 8; ++it) {
        int idx = tid + it * 256;  // float4 slot 0..2047
        int r = idx >> 5, c4 = idx & 31;
        float4 v = *(const float4*)(qkv + (size_t)(i0 + r) * QKV_D + h * HD + c4 * 4);
        v.x *= scale; v.y *= scale; v.z *= scale; v.w *= scale;
        *(float4*)&qs[r][c4 * 4] = v;
    }

    int rg = tid >> 4;        // row group 0..15
    int r0 = rg * 4;
    int c  = tid & 15;        // score col / PV d-chunk

    float m[4] = {-INFINITY, -INFINITY, -INFINITY, -INFINITY};
    float l[4] = {0.f, 0.f, 0.f, 0.f};
    float4 oA[4] = {}, oB[4] = {};

    for (int j0 = 0; j0 < i0 + QT; j0 += JT) {
        __syncthreads();  // prev PV done (and Q staged on first iter)
        // stage K/V tile
#pragma unroll
        for (int it = 0; it < 2; ++it) {
            int idx = tid + it * 256;  // 0..511
            int r = idx >> 5, c4 = idx & 31;
            const float* kb = qkv + (size_t)(j0 + r) * QKV_D + NH * HD + kvh * HD;
            *(float4*)&ks[r][c4 * 4] = *(const float4*)(kb + c4 * 4);
            *(float4*)&vs[r][c4 * 4] = *(const float4*)(kb + NKV * HD + c4 * 4);
        }
        __syncthreads();

        // scores: 4 rows x 1 col per thread
        float s0 = 0.f, s1 = 0.f, s2 = 0.f, s3 = 0.f;
#pragma unroll
        for (int dc = 0; dc < 32; ++dc) {
            float4 kv = *(const float4*)&ks[c][dc * 4];
            float4 q0 = *(const float4*)&qs[r0 + 0][dc * 4];
            float4 q1 = *(const float4*)&qs[r0 + 1][dc * 4];
            float4 q2 = *(const float4*)&qs[r0 + 2][dc * 4];
            float4 q3 = *(const float4*)&qs[r0 + 3][dc * 4];
            s0 += q0.x * kv.x + q0.y * kv.y + q0.z * kv.z + q0.w * kv.w;
            s1 += q1.x * kv.x + q1.y * kv.y + q1.z * kv.z + q1.w * kv.w;
            s2 += q2.x * kv.x + q2.y * kv.y + q2.z * kv.z + q2.w * kv.w;
            s3 += q3.x * kv.x + q3.y * kv.y + q3.z * kv.z + q3.w * kv.w;
        }
        // causal mask (only tiles straddling the diagonal)
        if (j0 + JT - 1 > i0 + r0) {
            int jj = j0 + c;
            s0 = (jj <= i0 + r0 + 0) ? s0 : -INFINITY;
            s1 = (jj <= i0 + r0 + 1) ? s1 : -INFINITY;
            s2 = (jj <= i0 + r0 + 2) ? s2 : -INFINITY;
            s3 = (jj <= i0 + r0 + 3) ? s3 : -INFINITY;
        }
        // row max over 16 lanes
        float t0 = s0, t1 = s1, t2 = s2, t3 = s3;
#pragma unroll
        for (int off = 1; off < 16; off <<= 1) {
            t0 = fmaxf(t0, __shfl_xor(t0, off));
            t1 = fmaxf(t1, __shfl_xor(t1, off));
            t2 = fmaxf(t2, __shfl_xor(t2, off));
            t3 = fmaxf(t3, __shfl_xor(t3, off));
        }
        float mn0 = fmaxf(m[0], t0), mn1 = fmaxf(m[1], t1);
        float mn2 = fmaxf(m[2], t2), mn3 = fmaxf(m[3], t3);
        float al0 = __expf(m[0] - mn0), al1 = __expf(m[1] - mn1);
        float al2 = __expf(m[2] - mn2), al3 = __expf(m[3] - mn3);
        float p0 = __expf(s0 - mn0), p1 = __expf(s1 - mn1);
        float p2 = __expf(s2 - mn2), p3 = __expf(s3 - mn3);
        m[0] = mn0; m[1] = mn1; m[2] = mn2; m[3] = mn3;
        // row sum of p
        float u0 = p0, u1 = p1, u2 = p2, u3 = p3;
#pragma unroll
        for (int off = 1; off < 16; off <<= 1) {
            u0 += __shfl_xor(u0, off);
            u1 += __shfl_xor(u1, off);
            u2 += __shfl_xor(u2, off);
            u3 += __shfl_xor(u3, off);
        }
        l[0] = l[0] * al0 + u0; l[1] = l[1] * al1 + u1;
        l[2] = l[2] * al2 + u2; l[3] = l[3] * al3 + u3;
        // write P^T
        float4 pv = make_float4(p0, p1, p2, p3);
        *(float4*)&pt[c][r0] = pv;
        __syncthreads();

        // PV: rescale o then accumulate
        float alv[4] = {al0, al1, al2, al3};
#pragma unroll
        for (int i = 0; i < 4; ++i) {
            oA[i].x *= alv[i]; oA[i].y *= alv[i]; oA[i].z *= alv[i]; oA[i].w *= alv[i];
            oB[i].x *= alv[i]; oB[i].y *= alv[i]; oB[i].z *= alv[i]; oB[i].w *= alv[i];
        }
#pragma unroll
        for (int j = 0; j < JT; ++j) {
            float4 p4 = *(const float4*)&pt[j][r0];
            float4 va = *(const float4*)&vs[j][c * 4];
            float4 vb = *(const float4*)&vs[j][64 + c * 4];
            oA[0].x += p4.x * va.x; oA[0].y += p4.x * va.y; oA[0].z += p4.x * va.z; oA[0].w += p4.x * va.w;
            oB[0].x += p4.x * vb.x; oB[0].y += p4.x * vb.y; oB[0].z += p4.x * vb.z; oB[0].w += p4.x * vb.w;
            oA[1].x += p4.y * va.x; oA[1].y += p4.y * va.y; oA[1].z += p4.y * va.z; oA[1].w += p4.y * va.w;
            oB[1].x += p4.y * vb.x; oB[1].y += p4.y * vb.y; oB[1].z += p4.y * vb.z; oB[1].w += p4.y * vb.w;
            oA[2].x += p4.z * va.x; oA[2].y += p4.z * va.y; oA[2].z += p4.z * va.z; oA[2].w += p4.z * va.w;
            oB[2].x += p4.z * vb.x; oB[2].y += p4.z * vb.y; oB[2].z += p4.z * vb.z; oB[2].w += p4.z * vb.w;
            oA[3].x += p4.w * va.x; oA[3].y += p4.w * va.y; oA[3].z += p4.w * va.z; oA[3].w += p4.w * va.w;
            oB[3].x += p4.w * vb.x; oB[3].y += p4.w * vb.y; oB[3].z += p4.w * vb.z; oB[3].w += p4.w * vb.w;
        }
    }

    // normalize + store
#pragma unroll
    for (int i = 0; i < 4; ++i) {
        float inv = 1.f / l[i];
        float* orow = out + (size_t)(i0 + r0 + i) * (NH * HD) + h * HD;
        float4 a = oA[i], b = oB[i];
        a.x *= inv; a.y *= inv; a.z *= inv; a.w *= inv;
        b.x *= inv; b.y *= inv; b.z *= inv; b.w *= inv;
        *(float4*)(orow + c * 4) = a;
        *(float4*)(orow + 64 + c * 4) = b;
    }
}

// ---------------- top-2 routing ----------------
__global__ __launch_bounds__(256) void topk_k(const float* __restrict__ elog,
                                              float* __restrict__ w_out,
                                              float* __restrict__ id_out,
                                              int* __restrict__ ids_int) {
    int row = blockIdx.x * 256 + threadIdx.x;
    if (row >= N_TOK) return;
    const float4* e4 = (const float4*)(elog + (size_t)row * NE);
    float4 a = e4[0], b = e4[1];
    float e[8] = {a.x, a.y, a.z, a.w, b.x, b.y, b.z, b.w};
    int id0 = 0;
    float b0 = e[0];
#pragma unroll
    for (int t = 1; t < 8; ++t)
        if (e[t] > b0) { b0 = e[t]; id0 = t; }
    int id1 = -1;
    float b1 = -INFINITY;
#pragma unroll
    for (int t = 0; t < 8; ++t)
        if (t != id0 && e[t] > b1) { b1 = e[t]; id1 = t; }
    float s = b0 + b1;
    w_out[row * 2 + 0] = b0 / s;
    w_out[row * 2 + 1] = b1 / s;
    id_out[row * 2 + 0] = (float)id0;
    id_out[row * 2 + 1] = (float)id1;
    ids_int[row * 2 + 0] = id0;
    ids_int[row * 2 + 1] = id1;
}

// ---------------- stable argsort of 4096 expert ids (counting rank) ----------------
__global__ __launch_bounds__(256) void sort_k(const int* __restrict__ ids,
                                              float* __restrict__ reorder_out,
                                              int* __restrict__ perm) {
    __shared__ int sh[N_TOK * TOPK];
    int tid = threadIdx.x;
    for (int r = tid; r < N_TOK * TOPK; r += 256) sh[r] = ids[r];
    __syncthreads();
    int i = blockIdx.x * 256 + tid;
    int e = sh[i];
    int rank = 0;
    for (int j = 0; j < N_TOK * TOPK; ++j) {
        int ej = sh[j];
        rank += (ej < e) ? 1 : ((ej == e && j < i) ? 1 : 0);
    }
    reorder_out[rank] = (float)i;
    perm[rank] = i;
}

// ---------------- permuted row gather ----------------
__global__ __launch_bounds__(256) void gather_k(const float* __restrict__ src,
                                                const int* __restrict__ perm,
                                                float* __restrict__ dst) {
    int r = blockIdx.x;
    int srow = perm[r] >> 1;  // // TOPK
    const float4* s4 = (const float4*)(src + (size_t)srow * H_DIM);
    float4* d4 = (float4*)(dst + (size_t)r * H_DIM);
    int tid = threadIdx.x;
#pragma unroll
    for (int k = 0; k < 4; ++k) d4[tid + k * 256] = s4[tid + k * 256];
}

extern "C" void kernel_launch(void* const* d_in, const int* in_sizes, int n_in,
                              void* d_out, int out_size, void* d_ws, size_t ws_size,
                              hipStream_t stream) {
    const int*   positions = (const int*)d_in[0];
    const float* hidden    = (const float*)d_in[1];
    const float* w_qkv     = (const float*)d_in[2];
    const float* w_o       = (const float*)d_in[3];
    // d_in[4] = w_gate: dead code in reference (router_logits unused)
    const float* rms_pre   = (const float*)d_in[5];
    const float* rms_post  = (const float*)d_in[6];
    const float* elog      = (const float*)d_in[7];
    float* out = (float*)d_out;

    char* ws = (char*)d_ws;
    float* bufA = (float*)(ws);                    // 32 MB: x_norm, later s
    float* bufB = (float*)(ws + 33554432ULL);      // 48+ MB: qkv
    float* bufC = (float*)(ws + 83886080ULL);      // 32 MB: attn_out
    float* bufD = (float*)(ws + 117440512ULL);     // 32 MB: out2 (post-norm)
    int* ids_int = (int*)(ws + 150994944ULL);      // 16 KB
    int* perm_int = (int*)(ws + 151011328ULL);     // 16 KB

    // 1. pre-attention RMSNorm
    rmsnorm_k<<<N_TOK, 256, 0, stream>>>(hidden, rms_pre, bufA);
    // 2. QKV projection: (2048x4096) @ (4096x6144)
    gemm64_k<<<dim3(QKV_D / 64, N_TOK / 64), 256, 0, stream>>>(bufA, w_qkv, bufB, QKV_D, nullptr);
    // 3. RoPE on q (32 heads) + k (8 heads), in place
    rope_k<<<dim3(N_TOK, NH + NKV), 64, 0, stream>>>(bufB, positions);
    // 4. causal GQA attention (tiled flash)
    attn_k<<<dim3(N_TOK / QT, NH), 256, 0, stream>>>(bufB, bufC);
    // 5. output projection + residual: (2048x4096) @ (4096x4096) + hidden
    gemm64_k<<<dim3(H_DIM / 64, N_TOK / 64), 256, 0, stream>>>(bufC, w_o, bufA, H_DIM, hidden);
    // 6. post-attention RMSNorm
    rmsnorm_k<<<N_TOK, 256, 0, stream>>>(bufA, rms_post, bufD);
    // 7. top-2 expert selection
    topk_k<<<N_TOK / 256, 256, 0, stream>>>(elog, out + OUT_W, out + OUT_IDS, ids_int);
    // 8. stable argsort of flattened expert ids
    sort_k<<<(N_TOK * TOPK) / 256, 256, 0, stream>>>(ids_int, out + OUT_REO, perm_int);
    // 9. permuted gather of post-norm output rows
    gather_k<<<N_TOK * TOPK, 256, 0, stream>>>(bufD, perm_int, out + OUT_PERM);
}

// Round 4
// 838.938 us; speedup vs baseline: 9.0210x; 5.0200x over previous
//
#include <hip/hip_runtime.h>
#include <hip/hip_bf16.h>
#include <math.h>

// Problem constants
#define N_TOK 2048
#define H_DIM 4096
#define NH 32
#define NKV 8
#define HD 128
#define QKV_D 6144   // (NH + 2*NKV) * HD
#define NE 8
#define TOPK 2

// d_out layout (floats): permuted_output | topk_weights | topk_ids | reorder_ids
#define OUT_PERM 0
#define OUT_W    16777216   // 4096*4096
#define OUT_IDS  16781312
#define OUT_REO  16785408

typedef __bf16 bf16x8 __attribute__((ext_vector_type(8)));
typedef float f32x4 __attribute__((ext_vector_type(4)));

typedef __attribute__((address_space(3))) void lds_void;
typedef __attribute__((address_space(1))) const void gbl_void;

__device__ __forceinline__ void gld16(const void* g, void* l) {
    // async global->LDS, 16B per lane; LDS dest = wave-uniform base + lane*16
    __builtin_amdgcn_global_load_lds((gbl_void*)g, (lds_void*)l, 16, 0, 0);
}

__device__ __forceinline__ unsigned short f2bf(float f) {
    union { float f; unsigned u; } v; v.f = f;
    unsigned r = v.u + 0x7fff + ((v.u >> 16) & 1);
    return (unsigned short)(r >> 16);
}
__device__ __forceinline__ unsigned pack2bf(float a, float b) {
    return (unsigned)f2bf(a) | ((unsigned)f2bf(b) << 16);
}

// ---------------- RMSNorm (fp32 in; fp32 or bf16 out) ----------------
__global__ __launch_bounds__(256) void rmsnorm_k(const float* __restrict__ x,
                                                 const float* __restrict__ w,
                                                 float* __restrict__ yf,
                                                 unsigned short* __restrict__ yb) {
    int row = blockIdx.x;
    int tid = threadIdx.x;
    const float4* x4 = (const float4*)(x + (size_t)row * H_DIM);
    const float4* w4 = (const float4*)w;
    float4 v[4];
    float ss = 0.f;
#pragma unroll
    for (int k = 0; k < 4; ++k) {
        v[k] = x4[tid + k * 256];
        ss += v[k].x * v[k].x + v[k].y * v[k].y + v[k].z * v[k].z + v[k].w * v[k].w;
    }
#pragma unroll
    for (int off = 32; off; off >>= 1) ss += __shfl_xor(ss, off);
    __shared__ float sacc[4];
    if ((tid & 63) == 0) sacc[tid >> 6] = ss;
    __syncthreads();
    float tot = sacc[0] + sacc[1] + sacc[2] + sacc[3];
    float sc = rsqrtf(tot * (1.0f / H_DIM) + 1e-6f);
#pragma unroll
    for (int k = 0; k < 4; ++k) {
        float4 ww = w4[tid + k * 256];
        float4 o;
        o.x = v[k].x * sc * ww.x;
        o.y = v[k].y * sc * ww.y;
        o.z = v[k].z * sc * ww.z;
        o.w = v[k].w * sc * ww.w;
        if (yf) {
            *(float4*)(yf + (size_t)row * H_DIM + (tid + k * 256) * 4) = o;
        } else {
            uint2 p;
            p.x = pack2bf(o.x, o.y);
            p.y = pack2bf(o.z, o.w);
            *(uint2*)(yb + (size_t)row * H_DIM + (tid + k * 256) * 4) = p;
        }
    }
}

// ---------------- transpose + fp32->bf16 weight conversion ----------------
// src[R][C] fp32 -> dst[C][R] bf16 (64x64 tiles)
__global__ __launch_bounds__(256) void convT_k(const float* __restrict__ src,
                                               unsigned short* __restrict__ dst,
                                               int R, int C) {
    __shared__ float t[64][68];
    int r0 = blockIdx.y * 64, c0 = blockIdx.x * 64;
    int tid = threadIdx.x;
    int lr = tid >> 4, lc = tid & 15;
#pragma unroll
    for (int it = 0; it < 4; ++it) {
        int r = lr + it * 16;
        float4 v = *(const float4*)(src + (size_t)(r0 + r) * C + c0 + lc * 4);
        *(float4*)&t[r][lc * 4] = v;
    }
    __syncthreads();
#pragma unroll
    for (int it = 0; it < 4; ++it) {
        int cc = lr + it * 16;
        uint2 o;
        o.x = pack2bf(t[lc * 4 + 0][cc], t[lc * 4 + 1][cc]);
        o.y = pack2bf(t[lc * 4 + 2][cc], t[lc * 4 + 3][cc]);
        *(uint2*)(dst + (size_t)(c0 + cc) * R + r0 + lc * 4) = o;
    }
}

// ---------------- bf16 MFMA GEMM: C[M x Nc] = A[M x 4096] @ Bt[Nc x 4096]^T (+res) ----
// 128x128 tile, BK=32, 4 waves (each 64x64), 16x16x32 MFMA, XOR-swizzled LDS.
__global__ __launch_bounds__(256) void gemm_k(const __hip_bfloat16* __restrict__ A,
                                              const __hip_bfloat16* __restrict__ Bt,
                                              float* __restrict__ C,
                                              const float* __restrict__ residual,
                                              int Ncols) {
    __shared__ __align__(16) __hip_bfloat16 As[128 * 32];
    __shared__ __align__(16) __hip_bfloat16 Bs[128 * 32];
    const int K = H_DIM;
    int tid = threadIdx.x, w = tid >> 6, lane = tid & 63;
    int quad = lane >> 4, l15 = lane & 15;
    int m0 = blockIdx.y * 128, n0 = blockIdx.x * 128;
    int wm = (w & 1) * 64, wn = (w >> 1) * 64;

    // staging: chunk ch covers LDS rows [ch*16, ch*16+16); 4 lanes per 64B row
    int ch0 = w * 2, ch1 = ch0 + 1;
    int ra0 = ch0 * 16 + (lane >> 2), ra1 = ch1 * 16 + (lane >> 2);
    int pa0 = (lane & 3) ^ (ra0 & 3), pa1 = (lane & 3) ^ (ra1 & 3);  // XOR swizzle
    const char* Ag0 = (const char*)(A + (size_t)(m0 + ra0) * K) + pa0 * 16;
    const char* Ag1 = (const char*)(A + (size_t)(m0 + ra1) * K) + pa1 * 16;
    const char* Bg0 = (const char*)(Bt + (size_t)(n0 + ra0) * K) + pa0 * 16;
    const char* Bg1 = (const char*)(Bt + (size_t)(n0 + ra1) * K) + pa1 * 16;
    char* Al0 = (char*)As + ch0 * 1024;
    char* Al1 = (char*)As + ch1 * 1024;
    char* Bl0 = (char*)Bs + ch0 * 1024;
    char* Bl1 = (char*)Bs + ch1 * 1024;

    f32x4 acc[4][4];
#pragma unroll
    for (int i = 0; i < 4; ++i)
#pragma unroll
        for (int j = 0; j < 4; ++j) acc[i][j] = (f32x4){0.f, 0.f, 0.f, 0.f};

    for (int k0 = 0; k0 < K; k0 += 32) {
        __syncthreads();
        gld16(Ag0 + (size_t)k0 * 2, Al0);
        gld16(Ag1 + (size_t)k0 * 2, Al1);
        gld16(Bg0 + (size_t)k0 * 2, Bl0);
        gld16(Bg1 + (size_t)k0 * 2, Bl1);
        __syncthreads();
        bf16x8 af[4], bfr[4];
#pragma unroll
        for (int mt = 0; mt < 4; ++mt) {
            int m = wm + mt * 16 + l15;
            af[mt] = *(const bf16x8*)((const char*)As + m * 64 + ((quad ^ (m & 3)) * 16));
        }
#pragma unroll
        for (int nt = 0; nt < 4; ++nt) {
            int n = wn + nt * 16 + l15;
            bfr[nt] = *(const bf16x8*)((const char*)Bs + n * 64 + ((quad ^ (n & 3)) * 16));
        }
#pragma unroll
        for (int mt = 0; mt < 4; ++mt)
#pragma unroll
            for (int nt = 0; nt < 4; ++nt)
                acc[mt][nt] = __builtin_amdgcn_mfma_f32_16x16x32_bf16(af[mt], bfr[nt], acc[mt][nt], 0, 0, 0);
    }
    // epilogue: C/D layout col=lane&15, row=quad*4+reg
#pragma unroll
    for (int mt = 0; mt < 4; ++mt)
#pragma unroll
        for (int nt = 0; nt < 4; ++nt)
#pragma unroll
            for (int r = 0; r < 4; ++r) {
                int row = m0 + wm + mt * 16 + quad * 4 + r;
                int col = n0 + wn + nt * 16 + l15;
                size_t off = (size_t)row * Ncols + col;
                float v = acc[mt][nt][r];
                if (residual) v += residual[off];
                C[off] = v;
            }
}

// ---------------- prep: RoPE + pack Qc (scaled bf16) and Kc (bf16, per-head rows) ----
__global__ __launch_bounds__(256) void prep_k(const float* __restrict__ qkv,
                                              const int* __restrict__ pos,
                                              unsigned short* __restrict__ Qc,
                                              unsigned short* __restrict__ Kc) {
    int row = blockIdx.x, tid = threadIdx.x;
    float fpos = (float)pos[row];
    const float scale = 0.08838834764831845f;  // 1/sqrt(128)
    const float lg = 0.20762050593045f;        // log2(10000)/64
#pragma unroll
    for (int it = 0; it < 8; ++it) {
        int pi = tid + it * 256;        // 0..2047 : q pairs
        int head = pi >> 6, t = pi & 63;
        float inv = exp2f(-(float)t * lg);
        float ang = fpos * inv;
        float s = __sinf(ang), c = __cosf(ang);
        const float* bp = qkv + (size_t)row * QKV_D + head * HD + t;
        float x1 = bp[0], x2 = bp[64];
        unsigned short* qb = Qc + (size_t)row * H_DIM + head * HD + t;
        qb[0]  = f2bf((x1 * c - x2 * s) * scale);
        qb[64] = f2bf((x2 * c + x1 * s) * scale);
    }
#pragma unroll
    for (int it = 0; it < 2; ++it) {
        int pi = tid + it * 256;        // 0..511 : k pairs
        int kvh = pi >> 6, t = pi & 63;
        float inv = exp2f(-(float)t * lg);
        float ang = fpos * inv;
        float s = __sinf(ang), c = __cosf(ang);
        const float* bp = qkv + (size_t)row * QKV_D + H_DIM + kvh * HD + t;
        float x1 = bp[0], x2 = bp[64];
        unsigned short* kb = Kc + ((size_t)kvh * N_TOK + row) * HD + t;
        kb[0]  = f2bf(x1 * c - x2 * s);
        kb[64] = f2bf(x2 * c + x1 * s);
    }
}

// ---------------- V transpose: qkv V section -> Vt[kvh][d][key] bf16 ----------------
__global__ __launch_bounds__(256) void vt_k(const float* __restrict__ qkv,
                                            unsigned short* __restrict__ Vt) {
    __shared__ float t[64][132];
    int j0 = blockIdx.x * 64, kvh = blockIdx.y, tid = threadIdx.x;
#pragma unroll
    for (int it = 0; it < 8; ++it) {
        int idx = tid + it * 256;   // float4 slots of 64x128
        int r = idx >> 5, c4 = idx & 31;
        float4 v = *(const float4*)(qkv + (size_t)(j0 + r) * QKV_D + (NH + NKV) * HD + kvh * HD + c4 * 4);
        *(float4*)&t[r][c4 * 4] = v;
    }
    __syncthreads();
    int d = tid >> 1, half = tid & 1;
    unsigned short* dst = Vt + ((size_t)kvh * HD + d) * N_TOK + j0 + half * 32;
    unsigned buf[16];
#pragma unroll
    for (int kk = 0; kk < 16; ++kk) {
        int k2 = half * 32 + kk * 2;
        buf[kk] = pack2bf(t[k2][d], t[k2 + 1][d]);
    }
#pragma unroll
    for (int v4 = 0; v4 < 4; ++v4)
        *(uint4*)(dst + v4 * 8) = make_uint4(buf[v4 * 4], buf[v4 * 4 + 1], buf[v4 * 4 + 2], buf[v4 * 4 + 3]);
}

// ---------------- bf16 MFMA flash attention ----------------
// block = 64 q-rows x 1 head, 4 waves (16 q-rows each). 32-key steps.
// S^T = K*Q^T (keys as M) -> per-lane scalar softmax state (q = lane&15).
// P repacked to A-layout via per-wave LDS round-trip; PV accumulates O (q=quad*4+reg, d=lane&15).
__global__ __launch_bounds__(256) void attn_k(const __hip_bfloat16* __restrict__ Qc,
                                              const __hip_bfloat16* __restrict__ Kc,
                                              const __hip_bfloat16* __restrict__ Vt,
                                              unsigned short* __restrict__ ao) {
    __shared__ __align__(16) __hip_bfloat16 Ks[32 * 128];   // [key][d], XOR-swizzled 16B units
    __shared__ __align__(16) __hip_bfloat16 Vs[128 * 32];   // [d][key], XOR-swizzled 16B units
    __shared__ __align__(16) unsigned short Pw[4][16 * 40]; // per-wave P, row stride 80B

    int tid = threadIdx.x, w = tid >> 6, lane = tid & 63;
    int quad = lane >> 4, l15 = lane & 15;
    int h = blockIdx.y, kvh = h >> 2;
    int qt = gridDim.x - 1 - blockIdx.x;    // heavy tiles first
    int i0 = qt * 64;
    int i0q = i0 + w * 16;
    int q = i0q + l15;

    // Q fragments (held in registers all kernel)
    bf16x8 qf[4];
    const __hip_bfloat16* qrow = Qc + (size_t)q * H_DIM + h * HD;
#pragma unroll
    for (int kf = 0; kf < 4; ++kf)
        qf[kf] = *(const bf16x8*)(qrow + kf * 32 + quad * 8);

    const char* KcH = (const char*)(Kc + (size_t)kvh * N_TOK * HD);
    const char* VtH = (const char*)(Vt + (size_t)kvh * HD * N_TOK);

    // staging lane assignments
    int chA = w * 2, chB = chA + 1;
    int kKeyA = chA * 4 + (lane >> 4), kKeyB = chB * 4 + (lane >> 4);
    int kPartA = (lane & 15) ^ (kKeyA & 15), kPartB = (lane & 15) ^ (kKeyB & 15);
    int vDA = chA * 16 + (lane >> 2), vDB = chB * 16 + (lane >> 2);
    int vPA = (lane & 3) ^ (vDA & 3), vPB = (lane & 3) ^ (vDB & 3);
    char* KlA = (char*)Ks + chA * 1024;
    char* KlB = (char*)Ks + chB * 1024;
    char* VlA = (char*)Vs + chA * 1024;
    char* VlB = (char*)Vs + chB * 1024;

    float mstat = -INFINITY, lstat = 0.f;
    f32x4 o[8];
#pragma unroll
    for (int nt = 0; nt < 8; ++nt) o[nt] = (f32x4){0.f, 0.f, 0.f, 0.f};

    for (int j0 = 0; j0 < i0 + 64; j0 += 32) {
        __syncthreads();
        gld16(KcH + (size_t)(j0 + kKeyA) * 256 + kPartA * 16, KlA);
        gld16(KcH + (size_t)(j0 + kKeyB) * 256 + kPartB * 16, KlB);
        gld16(VtH + (size_t)vDA * (N_TOK * 2) + (size_t)j0 * 2 + vPA * 16, VlA);
        gld16(VtH + (size_t)vDB * (N_TOK * 2) + (size_t)j0 * 2 + vPB * 16, VlB);
        __syncthreads();
        if (j0 > i0q + 15) continue;   // this wave's rows done (still staged for others)

        // S^T = K (MxK=32keys x 128d) * Q^T : D row=key(quad*4+reg), col=q(lane&15)
        f32x4 s[2];
        s[0] = (f32x4){0.f, 0.f, 0.f, 0.f};
        s[1] = (f32x4){0.f, 0.f, 0.f, 0.f};
#pragma unroll
        for (int mt = 0; mt < 2; ++mt) {
            int key = mt * 16 + l15;
#pragma unroll
            for (int kf = 0; kf < 4; ++kf) {
                bf16x8 kfr = *(const bf16x8*)((const char*)Ks + key * 256 + (((kf * 4 + quad) ^ (key & 15)) * 16));
                s[mt] = __builtin_amdgcn_mfma_f32_16x16x32_bf16(kfr, qf[kf], s[mt], 0, 0, 0);
            }
        }
        // causal mask (boundary steps only)
        if (j0 + 31 > i0q) {
#pragma unroll
            for (int mt = 0; mt < 2; ++mt) {
                int keyb = j0 + mt * 16 + quad * 4;
#pragma unroll
                for (int r = 0; r < 4; ++r)
                    if (keyb + r > q) s[mt][r] = -INFINITY;
            }
        }
        // online softmax (per-lane q; reduce over 8 regs + cross-quad)
        float mx = fmaxf(fmaxf(fmaxf(s[0][0], s[0][1]), fmaxf(s[0][2], s[0][3])),
                         fmaxf(fmaxf(s[1][0], s[1][1]), fmaxf(s[1][2], s[1][3])));
        mx = fmaxf(mx, __shfl_xor(mx, 16));
        mx = fmaxf(mx, __shfl_xor(mx, 32));
        float newm = fmaxf(mstat, mx);
        float alpha = __expf(mstat - newm);
        float p[8];
#pragma unroll
        for (int mt = 0; mt < 2; ++mt)
#pragma unroll
            for (int r = 0; r < 4; ++r) p[mt * 4 + r] = __expf(s[mt][r] - newm);
        float ps = p[0] + p[1] + p[2] + p[3] + p[4] + p[5] + p[6] + p[7];
        ps += __shfl_xor(ps, 16);
        ps += __shfl_xor(ps, 32);
        lstat = lstat * alpha + ps;
        mstat = newm;

        // P^T (q=lane&15, key=mt*16+quad*4+r) -> Pw[q][key] bf16, then read A-layout frag
        unsigned* pwb = (unsigned*)(&Pw[w][0]);
        int eo = l15 * 20 + quad * 2;   // u32 units
        pwb[eo]     = pack2bf(p[0], p[1]);
        pwb[eo + 1] = pack2bf(p[2], p[3]);
        pwb[eo + 8] = pack2bf(p[4], p[5]);
        pwb[eo + 9] = pack2bf(p[6], p[7]);
        bf16x8 pf = *(const bf16x8*)(&Pw[w][l15 * 40 + quad * 8]);

        // rescale O rows (row q = quad*4+r needs alpha from lane quad*4+r)
        float alq[4];
#pragma unroll
        for (int r = 0; r < 4; ++r) alq[r] = __shfl(alpha, quad * 4 + r);
#pragma unroll
        for (int nt = 0; nt < 8; ++nt)
#pragma unroll
            for (int r = 0; r < 4; ++r) o[nt][r] *= alq[r];

        // O += P(16q x 32k) * V(32k x 128d): D row=q(quad*4+reg), col=d(lane&15)
#pragma unroll
        for (int nt = 0; nt < 8; ++nt) {
            int d = nt * 16 + l15;
            bf16x8 vf = *(const bf16x8*)((const char*)Vs + d * 64 + ((quad ^ (d & 3)) * 16));
            o[nt] = __builtin_amdgcn_mfma_f32_16x16x32_bf16(pf, vf, o[nt], 0, 0, 0);
        }
    }

    // normalize + store bf16
    float linv[4];
#pragma unroll
    for (int r = 0; r < 4; ++r) linv[r] = 1.f / __shfl(lstat, quad * 4 + r);
#pragma unroll
    for (int nt = 0; nt < 8; ++nt)
#pragma unroll
        for (int r = 0; r < 4; ++r) {
            int row = i0q + quad * 4 + r;
            int col = h * HD + nt * 16 + l15;
            ao[(size_t)row * H_DIM + col] = f2bf(o[nt][r] * linv[r]);
        }
}

// ---------------- top-2 routing ----------------
__global__ __launch_bounds__(256) void topk_k(const float* __restrict__ elog,
                                              float* __restrict__ w_out,
                                              float* __restrict__ id_out,
                                              int* __restrict__ ids_int) {
    int row = blockIdx.x * 256 + threadIdx.x;
    if (row >= N_TOK) return;
    const float4* e4 = (const float4*)(elog + (size_t)row * NE);
    float4 a = e4[0], b = e4[1];
    float e[8] = {a.x, a.y, a.z, a.w, b.x, b.y, b.z, b.w};
    int id0 = 0;
    float b0 = e[0];
#pragma unroll
    for (int t = 1; t < 8; ++t)
        if (e[t] > b0) { b0 = e[t]; id0 = t; }
    int id1 = -1;
    float b1 = -INFINITY;
#pragma unroll
    for (int t = 0; t < 8; ++t)
        if (t != id0 && e[t] > b1) { b1 = e[t]; id1 = t; }
    float s = b0 + b1;
    w_out[row * 2 + 0] = b0 / s;
    w_out[row * 2 + 1] = b1 / s;
    id_out[row * 2 + 0] = (float)id0;
    id_out[row * 2 + 1] = (float)id1;
    ids_int[row * 2 + 0] = id0;
    ids_int[row * 2 + 1] = id1;
}

// ---------------- stable argsort of 4096 expert ids (counting rank) ----------------
__global__ __launch_bounds__(256) void sort_k(const int* __restrict__ ids,
                                              float* __restrict__ reorder_out,
                                              int* __restrict__ perm) {
    __shared__ int sh[N_TOK * TOPK];
    int tid = threadIdx.x;
    for (int r = tid; r < N_TOK * TOPK; r += 256) sh[r] = ids[r];
    __syncthreads();
    int i = blockIdx.x * 256 + tid;
    int e = sh[i];
    int rank = 0;
    for (int j = 0; j < N_TOK * TOPK; ++j) {
        int ej = sh[j];
        rank += (ej < e) ? 1 : ((ej == e && j < i) ? 1 : 0);
    }
    reorder_out[rank] = (float)i;
    perm[rank] = i;
}

// ---------------- permuted row gather ----------------
__global__ __launch_bounds__(256) void gather_k(const float* __restrict__ src,
                                                const int* __restrict__ perm,
                                                float* __restrict__ dst) {
    int r = blockIdx.x;
    int srow = perm[r] >> 1;  // // TOPK
    const float4* s4 = (const float4*)(src + (size_t)srow * H_DIM);
    float4* d4 = (float4*)(dst + (size_t)r * H_DIM);
    int tid = threadIdx.x;
#pragma unroll
    for (int k = 0; k < 4; ++k) d4[tid + k * 256] = s4[tid + k * 256];
}

extern "C" void kernel_launch(void* const* d_in, const int* in_sizes, int n_in,
                              void* d_out, int out_size, void* d_ws, size_t ws_size,
                              hipStream_t stream) {
    const int*   positions = (const int*)d_in[0];
    const float* hidden    = (const float*)d_in[1];
    const float* w_qkv     = (const float*)d_in[2];
    const float* w_o       = (const float*)d_in[3];
    // d_in[4] = w_gate: dead code in reference
    const float* rms_pre   = (const float*)d_in[5];
    const float* rms_post  = (const float*)d_in[6];
    const float* elog      = (const float*)d_in[7];
    float* out = (float*)d_out;

    char* ws = (char*)d_ws;
    // Overlapping lifetime plan (peak ~143 MB):
    unsigned short* wqkvT = (unsigned short*)(ws);                 // [0, 50.3M) until qkv-gemm
    unsigned short* woT   = (unsigned short*)(ws);                 // [0, 33.5M) conv2..o-gemm
    float*          post  = (float*)(ws + 33554432ULL);            // [33.5M, 67.1M) rms2..gather
    unsigned short* xn    = (unsigned short*)(ws + 50331648ULL);   // [50.3M, 67.1M) rms1..qkv-gemm
    unsigned short* aout  = (unsigned short*)(ws + 50331648ULL);   // [50.3M, 67.1M) attn..o-gemm
    float*          qkv   = (float*)(ws + 67108864ULL);            // [67.1M, 117.4M) gemm..vt
    float*          sbuf  = (float*)(ws + 67108864ULL);            // [67.1M, 100.7M) o-gemm..rms2
    unsigned short* Qc    = (unsigned short*)(ws + 117440512ULL);  // 16 MB
    unsigned short* Kc    = (unsigned short*)(ws + 134217728ULL);  // 4 MB
    unsigned short* Vt    = (unsigned short*)(ws + 138412032ULL);  // 4 MB
    int* ids_int  = (int*)(ws + 142606336ULL);
    int* perm_int = (int*)(ws + 142622720ULL);

    // 1. w_qkv -> bf16 transposed [6144][4096]
    convT_k<<<dim3(QKV_D / 64, H_DIM / 64), 256, 0, stream>>>(w_qkv, wqkvT, H_DIM, QKV_D);
    // 2. pre-attention RMSNorm -> bf16
    rmsnorm_k<<<N_TOK, 256, 0, stream>>>(hidden, rms_pre, nullptr, xn);
    // 3. QKV projection (bf16 MFMA) -> fp32 qkv
    gemm_k<<<dim3(QKV_D / 128, N_TOK / 128), 256, 0, stream>>>(
        (const __hip_bfloat16*)xn, (const __hip_bfloat16*)wqkvT, qkv, nullptr, QKV_D);
    // 4. w_o -> bf16 transposed [4096][4096]  (reuses wqkvT region)
    convT_k<<<dim3(H_DIM / 64, H_DIM / 64), 256, 0, stream>>>(w_o, woT, H_DIM, H_DIM);
    // 5. RoPE + pack Qc/Kc bf16
    prep_k<<<N_TOK, 256, 0, stream>>>(qkv, positions, Qc, Kc);
    // 6. V transpose -> Vt bf16
    vt_k<<<dim3(N_TOK / 64, NKV), 256, 0, stream>>>(qkv, Vt);
    // 7. causal GQA flash attention (bf16 MFMA) -> bf16 attn_out
    attn_k<<<dim3(N_TOK / 64, NH), 256, 0, stream>>>(
        (const __hip_bfloat16*)Qc, (const __hip_bfloat16*)Kc, (const __hip_bfloat16*)Vt, aout);
    // 8. output projection + residual (bf16 MFMA) -> fp32 s
    gemm_k<<<dim3(H_DIM / 128, N_TOK / 128), 256, 0, stream>>>(
        (const __hip_bfloat16*)aout, (const __hip_bfloat16*)woT, sbuf, hidden, H_DIM);
    // 9. post-attention RMSNorm -> fp32
    rmsnorm_k<<<N_TOK, 256, 0, stream>>>(sbuf, rms_post, post, nullptr);
    // 10. top-2 experts
    topk_k<<<N_TOK / 256, 256, 0, stream>>>(elog, out + OUT_W, out + OUT_IDS, ids_int);
    // 11. stable argsort of expert ids
    sort_k<<<(N_TOK * TOPK) / 256, 256, 0, stream>>>(ids_int, out + OUT_REO, perm_int);
    // 12. permuted gather
    gather_k<<<N_TOK * TOPK, 256, 0, stream>>>(post, perm_int, out + OUT_PERM);
}

// Round 5
// 831.362 us; speedup vs baseline: 9.1032x; 1.0091x over previous
//
#include <hip/hip_runtime.h>
#include <hip/hip_bf16.h>
#include <math.h>

// Problem constants
#define N_TOK 2048
#define H_DIM 4096
#define NH 32
#define NKV 8
#define HD 128
#define QKV_D 6144   // (NH + 2*NKV) * HD
#define NE 8
#define TOPK 2

// d_out layout (floats): permuted_output | topk_weights | topk_ids | reorder_ids
#define OUT_PERM 0
#define OUT_W    16777216   // 4096*4096
#define OUT_IDS  16781312
#define OUT_REO  16785408

typedef __bf16 bf16x8 __attribute__((ext_vector_type(8)));
typedef float f32x4 __attribute__((ext_vector_type(4)));

typedef __attribute__((address_space(3))) void lds_void;
typedef __attribute__((address_space(1))) const void gbl_void;

__device__ __forceinline__ void gld16(const void* g, void* l) {
    // async global->LDS, 16B per lane; LDS dest = wave-uniform base + lane*16
    __builtin_amdgcn_global_load_lds((gbl_void*)g, (lds_void*)l, 16, 0, 0);
}

__device__ __forceinline__ unsigned short f2bf(float f) {
    union { float f; unsigned u; } v; v.f = f;
    unsigned r = v.u + 0x7fff + ((v.u >> 16) & 1);
    return (unsigned short)(r >> 16);
}
__device__ __forceinline__ unsigned pack2bf(float a, float b) {
    return (unsigned)f2bf(a) | ((unsigned)f2bf(b) << 16);
}
__device__ __forceinline__ float bf2f(unsigned short u) {
    union { unsigned u; float f; } v; v.u = ((unsigned)u) << 16;
    return v.f;
}

// ---------------- RMSNorm (fp32 in; fp32 or bf16 out) ----------------
__global__ __launch_bounds__(256) void rmsnorm_k(const float* __restrict__ x,
                                                 const float* __restrict__ w,
                                                 float* __restrict__ yf,
                                                 unsigned short* __restrict__ yb) {
    int row = blockIdx.x;
    int tid = threadIdx.x;
    const float4* x4 = (const float4*)(x + (size_t)row * H_DIM);
    const float4* w4 = (const float4*)w;
    float4 v[4];
    float ss = 0.f;
#pragma unroll
    for (int k = 0; k < 4; ++k) {
        v[k] = x4[tid + k * 256];
        ss += v[k].x * v[k].x + v[k].y * v[k].y + v[k].z * v[k].z + v[k].w * v[k].w;
    }
#pragma unroll
    for (int off = 32; off; off >>= 1) ss += __shfl_xor(ss, off);
    __shared__ float sacc[4];
    if ((tid & 63) == 0) sacc[tid >> 6] = ss;
    __syncthreads();
    float tot = sacc[0] + sacc[1] + sacc[2] + sacc[3];
    float sc = rsqrtf(tot * (1.0f / H_DIM) + 1e-6f);
#pragma unroll
    for (int k = 0; k < 4; ++k) {
        float4 ww = w4[tid + k * 256];
        float4 o;
        o.x = v[k].x * sc * ww.x;
        o.y = v[k].y * sc * ww.y;
        o.z = v[k].z * sc * ww.z;
        o.w = v[k].w * sc * ww.w;
        if (yf) {
            *(float4*)(yf + (size_t)row * H_DIM + (tid + k * 256) * 4) = o;
        } else {
            uint2 p;
            p.x = pack2bf(o.x, o.y);
            p.y = pack2bf(o.z, o.w);
            *(uint2*)(yb + (size_t)row * H_DIM + (tid + k * 256) * 4) = p;
        }
    }
}

// ---------------- transpose + fp32->bf16 weight conversion ----------------
// src[R][C] fp32 -> dst[C][R] bf16 (64x64 tiles)
__global__ __launch_bounds__(256) void convT_k(const float* __restrict__ src,
                                               unsigned short* __restrict__ dst,
                                               int R, int C) {
    __shared__ float t[64][68];
    int r0 = blockIdx.y * 64, c0 = blockIdx.x * 64;
    int tid = threadIdx.x;
    int lr = tid >> 4, lc = tid & 15;
#pragma unroll
    for (int it = 0; it < 4; ++it) {
        int r = lr + it * 16;
        float4 v = *(const float4*)(src + (size_t)(r0 + r) * C + c0 + lc * 4);
        *(float4*)&t[r][lc * 4] = v;
    }
    __syncthreads();
#pragma unroll
    for (int it = 0; it < 4; ++it) {
        int cc = lr + it * 16;
        uint2 o;
        o.x = pack2bf(t[lc * 4 + 0][cc], t[lc * 4 + 1][cc]);
        o.y = pack2bf(t[lc * 4 + 2][cc], t[lc * 4 + 3][cc]);
        *(uint2*)(dst + (size_t)(c0 + cc) * R + r0 + lc * 4) = o;
    }
}

// ---------------- bf16 MFMA GEMM: C[M x Nc] = A[M x 4096] @ Bt[Nc x 4096]^T ----
// 128x64 tile (more blocks/CU), BK=32, 4 waves each 64x32, 16x16x32 MFMA, XOR-swizzled LDS.
// Output: bf16 (Cb) or fp32 + residual (C).
__global__ __launch_bounds__(256) void gemm_k(const __hip_bfloat16* __restrict__ A,
                                              const __hip_bfloat16* __restrict__ Bt,
                                              float* __restrict__ C,
                                              unsigned short* __restrict__ Cb,
                                              const float* __restrict__ residual,
                                              int Ncols) {
    __shared__ __align__(16) __hip_bfloat16 As[128 * 32];  // 8 KB
    __shared__ __align__(16) __hip_bfloat16 Bs[64 * 32];   // 4 KB
    const int K = H_DIM;
    int tid = threadIdx.x, w = tid >> 6, lane = tid & 63;
    int quad = lane >> 4, l15 = lane & 15;
    int m0 = blockIdx.x * 128, n0 = blockIdx.y * 64;
    int wm = (w & 1) * 64, wn = (w >> 1) * 32;

    // staging: A has 8 chunks of 16 rows (wave w -> chunks 2w,2w+1); B has 4 (wave w -> chunk w)
    int chA0 = w * 2, chA1 = chA0 + 1;
    int rA0 = chA0 * 16 + (lane >> 2), rA1 = chA1 * 16 + (lane >> 2);
    int rB  = w * 16 + (lane >> 2);
    int pA0 = (lane & 3) ^ (rA0 & 3), pA1 = (lane & 3) ^ (rA1 & 3);
    int pB  = (lane & 3) ^ (rB & 3);
    const char* Ag0 = (const char*)(A + (size_t)(m0 + rA0) * K) + pA0 * 16;
    const char* Ag1 = (const char*)(A + (size_t)(m0 + rA1) * K) + pA1 * 16;
    const char* Bg  = (const char*)(Bt + (size_t)(n0 + rB) * K) + pB * 16;
    char* Al0 = (char*)As + chA0 * 1024;
    char* Al1 = (char*)As + chA1 * 1024;
    char* Bl  = (char*)Bs + w * 1024;

    f32x4 acc[4][2];
#pragma unroll
    for (int i = 0; i < 4; ++i)
#pragma unroll
        for (int j = 0; j < 2; ++j) acc[i][j] = (f32x4){0.f, 0.f, 0.f, 0.f};

    for (int k0 = 0; k0 < K; k0 += 32) {
        __syncthreads();
        gld16(Ag0 + (size_t)k0 * 2, Al0);
        gld16(Ag1 + (size_t)k0 * 2, Al1);
        gld16(Bg + (size_t)k0 * 2, Bl);
        __syncthreads();
        bf16x8 af[4], bfr[2];
#pragma unroll
        for (int mt = 0; mt < 4; ++mt) {
            int m = wm + mt * 16 + l15;
            af[mt] = *(const bf16x8*)((const char*)As + m * 64 + ((quad ^ (m & 3)) * 16));
        }
#pragma unroll
        for (int nt = 0; nt < 2; ++nt) {
            int n = wn + nt * 16 + l15;
            bfr[nt] = *(const bf16x8*)((const char*)Bs + n * 64 + ((quad ^ (n & 3)) * 16));
        }
#pragma unroll
        for (int mt = 0; mt < 4; ++mt)
#pragma unroll
            for (int nt = 0; nt < 2; ++nt)
                acc[mt][nt] = __builtin_amdgcn_mfma_f32_16x16x32_bf16(af[mt], bfr[nt], acc[mt][nt], 0, 0, 0);
    }
    // epilogue: C/D layout col=lane&15, row=quad*4+reg
#pragma unroll
    for (int mt = 0; mt < 4; ++mt)
#pragma unroll
        for (int nt = 0; nt < 2; ++nt)
#pragma unroll
            for (int r = 0; r < 4; ++r) {
                int row = m0 + wm + mt * 16 + quad * 4 + r;
                int col = n0 + wn + nt * 16 + l15;
                size_t off = (size_t)row * Ncols + col;
                float v = acc[mt][nt][r];
                if (Cb) {
                    Cb[off] = f2bf(v);
                } else {
                    if (residual) v += residual[off];
                    C[off] = v;
                }
            }
}

// ---------------- prep: RoPE + pack Qc (scaled bf16) and Kc (bf16, per-head rows) ----
// reads bf16 qkv
__global__ __launch_bounds__(256) void prep_k(const unsigned short* __restrict__ qkvb,
                                              const int* __restrict__ pos,
                                              unsigned short* __restrict__ Qc,
                                              unsigned short* __restrict__ Kc) {
    int row = blockIdx.x, tid = threadIdx.x;
    float fpos = (float)pos[row];
    const float scale = 0.08838834764831845f;  // 1/sqrt(128)
    const float lg = 0.20762050593045f;        // log2(10000)/64
#pragma unroll
    for (int it = 0; it < 8; ++it) {
        int pi = tid + it * 256;        // 0..2047 : q pairs
        int head = pi >> 6, t = pi & 63;
        float inv = exp2f(-(float)t * lg);
        float ang = fpos * inv;
        float s = __sinf(ang), c = __cosf(ang);
        const unsigned short* bp = qkvb + (size_t)row * QKV_D + head * HD + t;
        float x1 = bf2f(bp[0]), x2 = bf2f(bp[64]);
        unsigned short* qb = Qc + (size_t)row * H_DIM + head * HD + t;
        qb[0]  = f2bf((x1 * c - x2 * s) * scale);
        qb[64] = f2bf((x2 * c + x1 * s) * scale);
    }
#pragma unroll
    for (int it = 0; it < 2; ++it) {
        int pi = tid + it * 256;        // 0..511 : k pairs
        int kvh = pi >> 6, t = pi & 63;
        float inv = exp2f(-(float)t * lg);
        float ang = fpos * inv;
        float s = __sinf(ang), c = __cosf(ang);
        const unsigned short* bp = qkvb + (size_t)row * QKV_D + H_DIM + kvh * HD + t;
        float x1 = bf2f(bp[0]), x2 = bf2f(bp[64]);
        unsigned short* kb = Kc + ((size_t)kvh * N_TOK + row) * HD + t;
        kb[0]  = f2bf(x1 * c - x2 * s);
        kb[64] = f2bf(x2 * c + x1 * s);
    }
}

// ---------------- V transpose: bf16 qkv V section -> Vt[kvh][d][key] ----------------
__global__ __launch_bounds__(256) void vt_k(const unsigned short* __restrict__ qkvb,
                                            unsigned short* __restrict__ Vt) {
    __shared__ unsigned short ts[64][136];
    int j0 = blockIdx.x * 64, kvh = blockIdx.y, tid = threadIdx.x;
#pragma unroll
    for (int it = 0; it < 4; ++it) {
        int idx = tid + it * 256;   // 16B slots of 64x128 ushort tile
        int r = idx >> 4, c8 = idx & 15;
        *(uint4*)&ts[r][c8 * 8] =
            *(const uint4*)(qkvb + (size_t)(j0 + r) * QKV_D + (NH + NKV) * HD + kvh * HD + c8 * 8);
    }
    __syncthreads();
    int d = tid >> 1, half = tid & 1;
    unsigned short* dst = Vt + ((size_t)kvh * HD + d) * N_TOK + j0 + half * 32;
#pragma unroll
    for (int g = 0; g < 4; ++g) {
        int kb = half * 32 + g * 8;
        uint4 o;
        o.x = (unsigned)ts[kb + 0][d] | ((unsigned)ts[kb + 1][d] << 16);
        o.y = (unsigned)ts[kb + 2][d] | ((unsigned)ts[kb + 3][d] << 16);
        o.z = (unsigned)ts[kb + 4][d] | ((unsigned)ts[kb + 5][d] << 16);
        o.w = (unsigned)ts[kb + 6][d] | ((unsigned)ts[kb + 7][d] << 16);
        *(uint4*)(dst + g * 8) = o;
    }
}

// ---------------- bf16 MFMA flash attention ----------------
// block = 64 q-rows x 1 head, 4 waves (16 q-rows each). 32-key steps.
__global__ __launch_bounds__(256) void attn_k(const __hip_bfloat16* __restrict__ Qc,
                                              const __hip_bfloat16* __restrict__ Kc,
                                              const __hip_bfloat16* __restrict__ Vt,
                                              unsigned short* __restrict__ ao) {
    __shared__ __align__(16) __hip_bfloat16 Ks[32 * 128];   // [key][d], XOR-swizzled 16B units
    __shared__ __align__(16) __hip_bfloat16 Vs[128 * 32];   // [d][key], XOR-swizzled 16B units
    __shared__ __align__(16) unsigned short Pw[4][16 * 40]; // per-wave P, row stride 80B

    int tid = threadIdx.x, w = tid >> 6, lane = tid & 63;
    int quad = lane >> 4, l15 = lane & 15;
    int h = blockIdx.y, kvh = h >> 2;
    int qt = gridDim.x - 1 - blockIdx.x;    // heavy tiles first
    int i0 = qt * 64;
    int i0q = i0 + w * 16;
    int q = i0q + l15;

    bf16x8 qf[4];
    const __hip_bfloat16* qrow = Qc + (size_t)q * H_DIM + h * HD;
#pragma unroll
    for (int kf = 0; kf < 4; ++kf)
        qf[kf] = *(const bf16x8*)(qrow + kf * 32 + quad * 8);

    const char* KcH = (const char*)(Kc + (size_t)kvh * N_TOK * HD);
    const char* VtH = (const char*)(Vt + (size_t)kvh * HD * N_TOK);

    int chA = w * 2, chB = chA + 1;
    int kKeyA = chA * 4 + (lane >> 4), kKeyB = chB * 4 + (lane >> 4);
    int kPartA = (lane & 15) ^ (kKeyA & 15), kPartB = (lane & 15) ^ (kKeyB & 15);
    int vDA = chA * 16 + (lane >> 2), vDB = chB * 16 + (lane >> 2);
    int vPA = (lane & 3) ^ (vDA & 3), vPB = (lane & 3) ^ (vDB & 3);
    char* KlA = (char*)Ks + chA * 1024;
    char* KlB = (char*)Ks + chB * 1024;
    char* VlA = (char*)Vs + chA * 1024;
    char* VlB = (char*)Vs + chB * 1024;

    float mstat = -INFINITY, lstat = 0.f;
    f32x4 o[8];
#pragma unroll
    for (int nt = 0; nt < 8; ++nt) o[nt] = (f32x4){0.f, 0.f, 0.f, 0.f};

    for (int j0 = 0; j0 < i0 + 64; j0 += 32) {
        __syncthreads();
        gld16(KcH + (size_t)(j0 + kKeyA) * 256 + kPartA * 16, KlA);
        gld16(KcH + (size_t)(j0 + kKeyB) * 256 + kPartB * 16, KlB);
        gld16(VtH + (size_t)vDA * (N_TOK * 2) + (size_t)j0 * 2 + vPA * 16, VlA);
        gld16(VtH + (size_t)vDB * (N_TOK * 2) + (size_t)j0 * 2 + vPB * 16, VlB);
        __syncthreads();
        if (j0 > i0q + 15) continue;   // this wave's rows done (still staged for others)

        // S^T = K (32keys x 128d) * Q^T : D row=key(quad*4+reg), col=q(lane&15)
        f32x4 s[2];
        s[0] = (f32x4){0.f, 0.f, 0.f, 0.f};
        s[1] = (f32x4){0.f, 0.f, 0.f, 0.f};
#pragma unroll
        for (int mt = 0; mt < 2; ++mt) {
            int key = mt * 16 + l15;
#pragma unroll
            for (int kf = 0; kf < 4; ++kf) {
                bf16x8 kfr = *(const bf16x8*)((const char*)Ks + key * 256 + (((kf * 4 + quad) ^ (key & 15)) * 16));
                s[mt] = __builtin_amdgcn_mfma_f32_16x16x32_bf16(kfr, qf[kf], s[mt], 0, 0, 0);
            }
        }
        if (j0 + 31 > i0q) {
#pragma unroll
            for (int mt = 0; mt < 2; ++mt) {
                int keyb = j0 + mt * 16 + quad * 4;
#pragma unroll
                for (int r = 0; r < 4; ++r)
                    if (keyb + r > q) s[mt][r] = -INFINITY;
            }
        }
        float mx = fmaxf(fmaxf(fmaxf(s[0][0], s[0][1]), fmaxf(s[0][2], s[0][3])),
                         fmaxf(fmaxf(s[1][0], s[1][1]), fmaxf(s[1][2], s[1][3])));
        mx = fmaxf(mx, __shfl_xor(mx, 16));
        mx = fmaxf(mx, __shfl_xor(mx, 32));
        float newm = fmaxf(mstat, mx);
        float alpha = __expf(mstat - newm);
        float p[8];
#pragma unroll
        for (int mt = 0; mt < 2; ++mt)
#pragma unroll
            for (int r = 0; r < 4; ++r) p[mt * 4 + r] = __expf(s[mt][r] - newm);
        float ps = p[0] + p[1] + p[2] + p[3] + p[4] + p[5] + p[6] + p[7];
        ps += __shfl_xor(ps, 16);
        ps += __shfl_xor(ps, 32);
        lstat = lstat * alpha + ps;
        mstat = newm;

        unsigned* pwb = (unsigned*)(&Pw[w][0]);
        int eo = l15 * 20 + quad * 2;   // u32 units
        pwb[eo]     = pack2bf(p[0], p[1]);
        pwb[eo + 1] = pack2bf(p[2], p[3]);
        pwb[eo + 8] = pack2bf(p[4], p[5]);
        pwb[eo + 9] = pack2bf(p[6], p[7]);
        bf16x8 pf = *(const bf16x8*)(&Pw[w][l15 * 40 + quad * 8]);

        float alq[4];
#pragma unroll
        for (int r = 0; r < 4; ++r) alq[r] = __shfl(alpha, quad * 4 + r);
#pragma unroll
        for (int nt = 0; nt < 8; ++nt)
#pragma unroll
            for (int r = 0; r < 4; ++r) o[nt][r] *= alq[r];

#pragma unroll
        for (int nt = 0; nt < 8; ++nt) {
            int d = nt * 16 + l15;
            bf16x8 vf = *(const bf16x8*)((const char*)Vs + d * 64 + ((quad ^ (d & 3)) * 16));
            o[nt] = __builtin_amdgcn_mfma_f32_16x16x32_bf16(pf, vf, o[nt], 0, 0, 0);
        }
    }

    float linv[4];
#pragma unroll
    for (int r = 0; r < 4; ++r) linv[r] = 1.f / __shfl(lstat, quad * 4 + r);
#pragma unroll
    for (int nt = 0; nt < 8; ++nt)
#pragma unroll
        for (int r = 0; r < 4; ++r) {
            int row = i0q + quad * 4 + r;
            int col = h * HD + nt * 16 + l15;
            ao[(size_t)row * H_DIM + col] = f2bf(o[nt][r] * linv[r]);
        }
}

// ---------------- top-2 routing ----------------
__global__ __launch_bounds__(256) void topk_k(const float* __restrict__ elog,
                                              float* __restrict__ w_out,
                                              float* __restrict__ id_out,
                                              int* __restrict__ ids_int) {
    int row = blockIdx.x * 256 + threadIdx.x;
    if (row >= N_TOK) return;
    const float4* e4 = (const float4*)(elog + (size_t)row * NE);
    float4 a = e4[0], b = e4[1];
    float e[8] = {a.x, a.y, a.z, a.w, b.x, b.y, b.z, b.w};
    int id0 = 0;
    float b0 = e[0];
#pragma unroll
    for (int t = 1; t < 8; ++t)
        if (e[t] > b0) { b0 = e[t]; id0 = t; }
    int id1 = -1;
    float b1 = -INFINITY;
#pragma unroll
    for (int t = 0; t < 8; ++t)
        if (t != id0 && e[t] > b1) { b1 = e[t]; id1 = t; }
    float s = b0 + b1;
    w_out[row * 2 + 0] = b0 / s;
    w_out[row * 2 + 1] = b1 / s;
    id_out[row * 2 + 0] = (float)id0;
    id_out[row * 2 + 1] = (float)id1;
    ids_int[row * 2 + 0] = id0;
    ids_int[row * 2 + 1] = id1;
}

// ---------------- stable argsort of 4096 expert ids (counting rank) ----------------
__global__ __launch_bounds__(256) void sort_k(const int* __restrict__ ids,
                                              float* __restrict__ reorder_out,
                                              int* __restrict__ perm) {
    __shared__ int sh[N_TOK * TOPK];
    int tid = threadIdx.x;
    for (int r = tid; r < N_TOK * TOPK; r += 256) sh[r] = ids[r];
    __syncthreads();
    int i = blockIdx.x * 256 + tid;
    int e = sh[i];
    int rank = 0;
    for (int j = 0; j < N_TOK * TOPK; ++j) {
        int ej = sh[j];
        rank += (ej < e) ? 1 : ((ej == e && j < i) ? 1 : 0);
    }
    reorder_out[rank] = (float)i;
    perm[rank] = i;
}

// ---------------- permuted row gather ----------------
__global__ __launch_bounds__(256) void gather_k(const float* __restrict__ src,
                                                const int* __restrict__ perm,
                                                float* __restrict__ dst) {
    int r = blockIdx.x;
    int srow = perm[r] >> 1;  // // TOPK
    const float4* s4 = (const float4*)(src + (size_t)srow * H_DIM);
    float4* d4 = (float4*)(dst + (size_t)r * H_DIM);
    int tid = threadIdx.x;
#pragma unroll
    for (int k = 0; k < 4; ++k) d4[tid + k * 256] = s4[tid + k * 256];
}

extern "C" void kernel_launch(void* const* d_in, const int* in_sizes, int n_in,
                              void* d_out, int out_size, void* d_ws, size_t ws_size,
                              hipStream_t stream) {
    const int*   positions = (const int*)d_in[0];
    const float* hidden    = (const float*)d_in[1];
    const float* w_qkv     = (const float*)d_in[2];
    const float* w_o       = (const float*)d_in[3];
    // d_in[4] = w_gate: dead code in reference
    const float* rms_pre   = (const float*)d_in[5];
    const float* rms_post  = (const float*)d_in[6];
    const float* elog      = (const float*)d_in[7];
    float* out = (float*)d_out;

    char* ws = (char*)d_ws;
    unsigned short* wqkvT = (unsigned short*)(ws);                 // [0, 50.3M) until qkv-gemm
    unsigned short* woT   = (unsigned short*)(ws);                 // [0, 33.5M) conv2..o-gemm
    float*          post  = (float*)(ws + 33554432ULL);            // [33.5M, 67.1M) rms2..gather
    unsigned short* xn    = (unsigned short*)(ws + 50331648ULL);   // [50.3M, 67.1M) rms1..qkv-gemm
    unsigned short* aout  = (unsigned short*)(ws + 50331648ULL);   // [50.3M, 67.1M) attn..o-gemm
    unsigned short* qkvb  = (unsigned short*)(ws + 67108864ULL);   // [67.1M, 92.3M) bf16 qkv
    float*          sbuf  = (float*)(ws + 67108864ULL);            // [67.1M, 100.7M) o-gemm..rms2
    unsigned short* Qc    = (unsigned short*)(ws + 117440512ULL);  // 16 MB
    unsigned short* Kc    = (unsigned short*)(ws + 134217728ULL);  // 4 MB
    unsigned short* Vt    = (unsigned short*)(ws + 138412032ULL);  // 4 MB
    int* ids_int  = (int*)(ws + 142606336ULL);
    int* perm_int = (int*)(ws + 142622720ULL);

    // 1. w_qkv -> bf16 transposed [6144][4096]
    convT_k<<<dim3(QKV_D / 64, H_DIM / 64), 256, 0, stream>>>(w_qkv, wqkvT, H_DIM, QKV_D);
    // 2. pre-attention RMSNorm -> bf16
    rmsnorm_k<<<N_TOK, 256, 0, stream>>>(hidden, rms_pre, nullptr, xn);
    // 3. QKV projection (bf16 MFMA) -> bf16 qkv
    gemm_k<<<dim3(N_TOK / 128, QKV_D / 64), 256, 0, stream>>>(
        (const __hip_bfloat16*)xn, (const __hip_bfloat16*)wqkvT, nullptr, qkvb, nullptr, QKV_D);
    // 4. w_o -> bf16 transposed [4096][4096]  (reuses wqkvT region)
    convT_k<<<dim3(H_DIM / 64, H_DIM / 64), 256, 0, stream>>>(w_o, woT, H_DIM, H_DIM);
    // 5. RoPE + pack Qc/Kc bf16
    prep_k<<<N_TOK, 256, 0, stream>>>(qkvb, positions, Qc, Kc);
    // 6. V transpose -> Vt bf16
    vt_k<<<dim3(N_TOK / 64, NKV), 256, 0, stream>>>(qkvb, Vt);
    // 7. causal GQA flash attention (bf16 MFMA) -> bf16 attn_out
    attn_k<<<dim3(N_TOK / 64, NH), 256, 0, stream>>>(
        (const __hip_bfloat16*)Qc, (const __hip_bfloat16*)Kc, (const __hip_bfloat16*)Vt, aout);
    // 8. output projection + residual (bf16 MFMA) -> fp32 s
    gemm_k<<<dim3(N_TOK / 128, H_DIM / 64), 256, 0, stream>>>(
        (const __hip_bfloat16*)aout, (const __hip_bfloat16*)woT, sbuf, nullptr, hidden, H_DIM);
    // 9. post-attention RMSNorm -> fp32
    rmsnorm_k<<<N_TOK, 256, 0, stream>>>(sbuf, rms_post, post, nullptr);
    // 10. top-2 experts
    topk_k<<<N_TOK / 256, 256, 0, stream>>>(elog, out + OUT_W, out + OUT_IDS, ids_int);
    // 11. stable argsort of expert ids
    sort_k<<<(N_TOK * TOPK) / 256, 256, 0, stream>>>(ids_int, out + OUT_REO, perm_int);
    // 12. permuted gather
    gather_k<<<N_TOK * TOPK, 256, 0, stream>>>(post, perm_int, out + OUT_PERM);
}